// Round 4
// baseline (3899.169 us; speedup 1.0000x reference)
//
#include <hip/hip_runtime.h>

// LSTM scan, B=64, T=16384, H=32, I=O=1, fp32.
// ONE WAVE PER BATCH (64 blocks x 64 threads). Issue-bound: VALUBusy ~5.3%
// against a 6.25% ceiling (64 waves / 1024 SIMDs) => the wave issues nearly
// every cycle; wall time ~ dynamic instructions per step.
//
// Round-8:
//  (a) Weight residency, attacked at the ROOT: VGPR_Count has been 60-64 in
//      every round while per-lane weights alone are 64 floats -> the backend
//      has been sinking/re-fetching weights inside the loop. Its register
//      budget comes from the waves-per-EU occupancy target, not from
//      launch_bounds. amdgpu_waves_per_eu(1,1) sets the pressure limit to
//      the full 512-VGPR file, so the hoisted weights survive allocation.
//      (Round-6 PIN failed: "+v" forces a def, not residency; RA re-spilled.)
//  (b) Movless matvec: scalar v_fmac chains, readlane result used directly
//      as the SGPR operand (VOP2 src0). Per k: 1 readlane + 2 fmac, no
//      pack-movs, no end-of-chain pair reduce. Two interleaved chains give
//      6-cyc spacing >= FMA latency -> no bubbles.
//  (c) Round-7 LDS broadcast reverted (serial LDS roundtrip cost ~250 cyc:
//      VALUBusy dropped 5.0->3.1 while dur rose). h_hist is epilogue-only
//      again, row stride 65 = conflict-free.
//  Round-5/6 algebra kept: pre-scaled weights; C = -2*log2(e)*c so every
//  transcendental is bare exp2 -> add -> rcp; h = fma(sig(2c), 2o, -o);
//  A-lane p = fma(r2, 2KT*i, -KT*i).
//
// Lane mapping (validated round 4): j = lane&31, half = lane>>5.
//   A-lanes (half=0): gates i (row j)    and g (row 64+j)
//   B-lanes (half=1): gates f (row 32+j) and o (row 96+j)
// B-lanes hold the real C,h. A-lanes compute bounded garbage (q_A = KT*f*o
// in (KT,0), a1 in (0,1) -> C_A negative, finite; h_A in (-1,1)).
// Cross-half exchange: permlane32_swap builtin + XOR identity (known-good).

#define HID 32
#define CHUNK 32

typedef float f4 __attribute__((ext_vector_type(4)));
typedef unsigned int u32x2 __attribute__((ext_vector_type(2)));

#if defined(__has_builtin)
#if __has_builtin(__builtin_amdgcn_permlane32_swap)
#define HAVE_PLSWAP 1
#endif
#endif

__device__ __forceinline__ float rl(float v, int lane) {
    return __int_as_float(__builtin_amdgcn_readlane(__float_as_int(v), lane));
}

// Exchange p across wave halves: every lane gets the other half's p
// (for its own j). Exact XOR recombination, orientation-independent.
__device__ __forceinline__ float cross_half(float p) {
#ifdef HAVE_PLSWAP
    const unsigned pu = __float_as_uint(p);
    u32x2 r = __builtin_amdgcn_permlane32_swap(pu, pu, false, false);
    return __uint_as_float(r[0] ^ r[1] ^ pu);
#else
    return __shfl_xor(p, 32, 64);
#endif
}

__global__
__attribute__((amdgpu_flat_work_group_size(64, 64)))
__attribute__((amdgpu_waves_per_eu(1, 1)))
void lstm_wave_scan(const float* __restrict__ x,
                    const float* __restrict__ W_ih,
                    const float* __restrict__ W_hh,
                    const float* __restrict__ b_ih,
                    const float* __restrict__ b_hh,
                    const float* __restrict__ W_lin,
                    const float* __restrict__ b_lin,
                    float* __restrict__ out,
                    int T) {
    __shared__ float h_hist[CHUNK][65];   // stride 65: epilogue conflict-free

    const int lane = threadIdx.x;
    const int j    = lane & 31;
    const int half = lane >> 5;
    const int b    = blockIdx.x;

    const int row1 = j + (half << 5);         // A: i-row j     B: f-row 32+j
    const int row2 = 64 + j + (half << 5);    // A: g-row 64+j  B: o-row 96+j

    const float K1 = -1.44269504088896340736f;   // -log2(e): sigmoid arg scale
    const float KT = -2.88539008177792681472f;   // -2*log2(e): tanh-as-sigmoid
    const float K2 = half ? K1 : KT;             // gate2: B=o (sig), A=g (tanh)
    const float cu = half ? KT : 2.0f * KT;      // p = fma(r2, cu*a1, cv*a1)
    const float cv = half ? 0.0f : -KT;          //   (p lives in C-space)

    // Load + pre-scale weights (once). Scalar floats: easiest for RA to
    // keep resident under the 512-VGPR budget.
    float w1s[HID], w2s[HID];
    {
        const f4* R1 = (const f4*)(W_hh + row1 * HID);
        const f4* R2 = (const f4*)(W_hh + row2 * HID);
#pragma unroll
        for (int m = 0; m < 8; ++m) {
            f4 v1 = R1[m];
            w1s[4*m+0] = v1.x * K1; w1s[4*m+1] = v1.y * K1;
            w1s[4*m+2] = v1.z * K1; w1s[4*m+3] = v1.w * K1;
            f4 v2 = R2[m];
            w2s[4*m+0] = v2.x * K2; w2s[4*m+1] = v2.y * K2;
            w2s[4*m+2] = v2.z * K2; w2s[4*m+3] = v2.w * K2;
        }
    }
    const float wih1 = W_ih[row1] * K1;
    const float bb1  = (b_ih[row1] + b_hh[row1]) * K1;
    const float wih2 = W_ih[row2] * K2;
    const float bb2  = (b_ih[row2] + b_hh[row2]) * K2;
    const float blin = b_lin[0];

    // Epilogue weights register-resident too (budget allows).
    float wl[HID];
    {
        const f4* RL = (const f4*)W_lin;
#pragma unroll
        for (int m = 0; m < 8; ++m) {
            f4 v = RL[m];
            wl[4*m+0] = v.x; wl[4*m+1] = v.y; wl[4*m+2] = v.z; wl[4*m+3] = v.w;
        }
    }

    float C = 0.0f;     // B-lanes: KT * cell state  (A-lanes: bounded garbage)
    float h = 0.0f;     // B-lanes: hidden state

    const float* xb = x   + (size_t)b * T;
    float*       ob = out + (size_t)b * T;

    float xv = xb[j];

    for (int t0 = 0; t0 < T; t0 += CHUNK) {
        int t0n = t0 + CHUNK; if (t0n >= T) t0n = 0;
        float xv_next = xb[t0n + j];

#pragma unroll 8
        for (int tt = 0; tt < CHUNK; ++tt) {
            const float sx = rl(xv, tt);  // wave-uniform x_t

            // Movless matvec: per k, 1 readlane (SGPR) + 2 v_fmac with the
            // SGPR as src0. Two interleaved chains -> no latency bubbles.
            float a1acc = __builtin_fmaf(sx, wih1, bb1);
            float a2acc = __builtin_fmaf(sx, wih2, bb2);
#pragma unroll
            for (int k = 0; k < HID; ++k) {
                const float hs = rl(h, 32 + k);   // uniform -> SGPR operand
                a1acc = __builtin_fmaf(hs, w1s[k], a1acc);
                a2acc = __builtin_fmaf(hs, w2s[k], a2acc);
            }
            const float m1 = a1acc;     // A: K1*i-pre   B: K1*f-pre
            const float m2 = a2acc;     // A: KT*g-pre   B: K1*o-pre

            // bare exp2 -> add -> rcp (scales pre-folded into m1/m2)
            const float a1 = __builtin_amdgcn_rcpf(1.0f + __builtin_amdgcn_exp2f(m1));
            const float r2 = __builtin_amdgcn_rcpf(1.0f + __builtin_amdgcn_exp2f(m2));

            const float uu = cu * a1;       // off the r2 chain (parallel)
            const float vv = cv * a1;
            const float o2 = r2 + r2;       // off the C chain
            const float on = -r2;

            const float p = __builtin_fmaf(r2, uu, vv);
                                            // A: KT*i*tanh(g)   B: KT*f*o
            const float q = cross_half(p);  // A: KT*f*o         B: KT*i*tanh(g)

            C = __builtin_fmaf(a1, C, q);   // B: KT*(f*c + i*g~)
            const float sg = __builtin_amdgcn_rcpf(1.0f + __builtin_amdgcn_exp2f(C));
                                            // B: sigmoid(2c)
            h = __builtin_fmaf(sg, o2, on); // B: o*(2*sig(2c)-1) = o*tanh(c)

            h_hist[tt][lane] = h;           // cols 32..63 = real h (epilogue)
        }

        // ---- epilogue: out[b][t0+t'] = x + W_lin . h_t' + b_lin, t' = j
        {
            float fa = 0.0f, fb = 0.0f, fc = 0.0f, fd = 0.0f;
#pragma unroll
            for (int k = 0; k < 8; ++k) {
                fa = __builtin_fmaf(wl[4*k+0], h_hist[j][32 + 4*k+0], fa);
                fb = __builtin_fmaf(wl[4*k+1], h_hist[j][32 + 4*k+1], fb);
                fc = __builtin_fmaf(wl[4*k+2], h_hist[j][32 + 4*k+2], fc);
                fd = __builtin_fmaf(wl[4*k+3], h_hist[j][32 + 4*k+3], fd);
            }
            if (half == 0)
                ob[t0 + j] = xv + ((fa + fb) + (fc + fd)) + blin;
        }

        xv = xv_next;
    }
}

extern "C" void kernel_launch(void* const* d_in, const int* in_sizes, int n_in,
                              void* d_out, int out_size, void* d_ws, size_t ws_size,
                              hipStream_t stream) {
    const float* x     = (const float*)d_in[0];
    const float* W_ih  = (const float*)d_in[1];
    const float* W_hh  = (const float*)d_in[2];
    const float* b_ih  = (const float*)d_in[3];
    const float* b_hh  = (const float*)d_in[4];
    const float* W_lin = (const float*)d_in[5];
    const float* b_lin = (const float*)d_in[6];
    float* out = (float*)d_out;

    const int B = 64;
    const int T = in_sizes[0] / B;   // 16384

    dim3 grid(B);
    dim3 block(64);
    lstm_wave_scan<<<grid, block, 0, stream>>>(x, W_ih, W_hh, b_ih, b_hh,
                                               W_lin, b_lin, out, T);
}

// Round 6
// 3433.023 us; speedup vs baseline: 1.1358x; 1.1358x over previous
//
#include <hip/hip_runtime.h>
#include <stdint.h>

// LSTM scan, B=64, T=16384, H=32, I=O=1, fp32.
// ONE WAVE PER BATCH (64 blocks x 64 threads). Issue-bound: VALUBusy ~5.3%
// vs the 6.25% ceiling (64 waves / 1024 SIMDs) => the active SIMD issues
// ~85% of cycles; wall time ~ dynamic VALU instructions per step.
//
// Round-10: resubmit of round-9 (harness container failure, no kernel
// verdict). EXACT round-4 baseline (best measured: 3223 us steady) with ONE
// change: the matvec's h-broadcast pairs are fed to v_pk_fma_f32 as SGPR
// PAIRS via inline asm, instead of being packed into VGPR pairs with v_movs.
//   R4 per m: 2 v_readlane + 2 v_mov + 2 v_pk_fma  (6 instrs)
//   R9 per m: 2 v_readlane + 2 v_pk_fma            (4 instrs)
// VOP3P sources may be 64-bit scalar (SGPR-pair) operands - one scalar read,
// legal. readlane results are uniform -> already SGPRs; ((u64)hi<<32)|lo is
// a REG_SEQUENCE (no instructions). Saves 32 v_movs = ~64 issue-cycles of
// the ~480-cycle step.
// Post-mortems driving this: R5 (more chains) +instrs -> slower; R6 (PIN)
// scheduling constraint -> slower; R7 (LDS broadcast) serial DS roundtrip
// -> slower; R8 (scalar fmac + waves_per_eu(1,1)) weights resident (VGPR
// 132) yet slower => residency irrelevant, instruction count is everything.
//
// Lane mapping (validated): j = lane&31, half = lane>>5.
//   A-lanes (half=0): gates i (row j)    and g (row 64+j)
//   B-lanes (half=1): gates f (row 32+j) and o (row 96+j)
// c,h valid in B-lanes (A-lanes compute bounded garbage: their "c" update is
// c = i*c + f*o with i in (0,1) -> contraction, no overflow).
// Cross-half exchange: permlane32_swap builtin + XOR identity (exact,
// orientation-independent, known-good).

#define HID 32
#define CHUNK 32

typedef float f2 __attribute__((ext_vector_type(2)));
typedef float f4 __attribute__((ext_vector_type(4)));
typedef unsigned int u32x2 __attribute__((ext_vector_type(2)));

#if defined(__has_builtin)
#if __has_builtin(__builtin_amdgcn_permlane32_swap)
#define HAVE_PLSWAP 1
#endif
#endif

__device__ __forceinline__ float rl(float v, int lane) {
    return __int_as_float(__builtin_amdgcn_readlane(__float_as_int(v), lane));
}
__device__ __forceinline__ unsigned rlu(float v, int lane) {
    return (unsigned)__builtin_amdgcn_readlane(__float_as_int(v), lane);
}

__device__ __forceinline__ float fsig(float v) {
    float e = __builtin_amdgcn_exp2f(v * -1.44269504088896340736f);
    return __builtin_amdgcn_rcpf(1.0f + e);
}
__device__ __forceinline__ float ftanh(float v) {
    float e = __builtin_amdgcn_exp2f(v * -2.88539008177792681472f);
    float r = __builtin_amdgcn_rcpf(1.0f + e);
    return __builtin_fmaf(2.0f, r, -1.0f);
}

// Exchange p across wave halves: every lane gets the other half's p
// (for its own j). VALU-only on gfx950; DS-pipe fallback otherwise.
__device__ __forceinline__ float cross_half(float p) {
#ifdef HAVE_PLSWAP
    const unsigned pu = __float_as_uint(p);
    u32x2 r = __builtin_amdgcn_permlane32_swap(pu, pu, false, false);
    return __uint_as_float(r[0] ^ r[1] ^ pu);   // exact, orientation-independent
#else
    return __shfl_xor(p, 32, 64);
#endif
}

__global__ __launch_bounds__(64, 1)
void lstm_wave_scan(const float* __restrict__ x,
                    const float* __restrict__ W_ih,
                    const float* __restrict__ W_hh,
                    const float* __restrict__ b_ih,
                    const float* __restrict__ b_hh,
                    const float* __restrict__ W_lin,
                    const float* __restrict__ b_lin,
                    float* __restrict__ out,
                    int T) {
    __shared__ float h_hist[CHUNK][65];   // row stride 65: epilogue conflict-free

    const int lane = threadIdx.x;
    const int j    = lane & 31;
    const int half = lane >> 5;
    const int b    = blockIdx.x;

    const int row1 = j + (half << 5);         // A: i-row j     B: f-row 32+j
    const int row2 = 64 + j + (half << 5);    // A: g-row 64+j  B: o-row 96+j

    f2 w1[16], w2[16];
    {
        const f4* R1 = (const f4*)(W_hh + row1 * HID);
        const f4* R2 = (const f4*)(W_hh + row2 * HID);
#pragma unroll
        for (int m = 0; m < 8; ++m) {
            f4 v;
            v = R1[m]; w1[2*m] = f2{v.x, v.y}; w1[2*m+1] = f2{v.z, v.w};
            v = R2[m]; w2[2*m] = f2{v.x, v.y}; w2[2*m+1] = f2{v.z, v.w};
        }
    }
    const float wih1 = W_ih[row1], bb1 = b_ih[row1] + b_hh[row1];
    const float wih2 = W_ih[row2], bb2 = b_ih[row2] + b_hh[row2];

    // act2: A-lanes tanh (g), B-lanes sigmoid (o):
    //   act2(v) = pb * rcp(1 + exp2(pa*v)) + pc
    const float pa = half ? -1.44269504088896340736f : -2.88539008177792681472f;
    const float pb = half ? 1.0f : 2.0f;
    const float pc = half ? 0.0f : -1.0f;

    const float blin = b_lin[0];

    float c = 0.0f;     // B-lanes: cell state (A-lanes: bounded garbage)
    float h = 0.0f;     // B-lanes: hidden state h_{t-1}

    const float* xb = x   + (size_t)b * T;
    float*       ob = out + (size_t)b * T;

    float xv = xb[j];

    for (int t0 = 0; t0 < T; t0 += CHUNK) {
        int t0n = t0 + CHUNK; if (t0n >= T) t0n = 0;
        float xv_next = xb[t0n + j];

#pragma unroll 8
        for (int tt = 0; tt < CHUNK; ++tt) {
            const float sx = rl(xv, tt);  // wave-uniform x_t

            f2 acc1 = f2{ __builtin_fmaf(sx, wih1, bb1), 0.0f };
            f2 acc2 = f2{ __builtin_fmaf(sx, wih2, bb2), 0.0f };
            // Matvec with fused h-broadcast. The readlane pair lands in an
            // SGPR pair (REG_SEQUENCE, no pack instrs) and feeds v_pk_fma_f32
            // directly as a 64-bit scalar operand: per m, 2 readlane +
            // 2 pk_fma, zero v_movs.
#pragma unroll
            for (int m = 0; m < 16; ++m) {
                const unsigned lo = rlu(h, 32 + 2*m);
                const unsigned hi = rlu(h, 32 + 2*m + 1);
                const uint64_t hp = ((uint64_t)hi << 32) | (uint64_t)lo;
                asm("v_pk_fma_f32 %0, %1, %2, %0"
                    : "+v"(acc1) : "v"(w1[m]), "s"(hp));
                asm("v_pk_fma_f32 %0, %1, %2, %0"
                    : "+v"(acc2) : "v"(w2[m]), "s"(hp));
            }
            const float g1 = acc1.x + acc1.y;   // A: i-pre   B: f-pre
            const float g2 = acc2.x + acc2.y;   // A: g-pre   B: o-pre

            const float a1 = fsig(g1);          // A: i       B: f
            const float e2 = __builtin_amdgcn_exp2f(g2 * pa);
            const float a2 = __builtin_fmaf(pb, __builtin_amdgcn_rcpf(1.0f + e2), pc);
                                                // A: g       B: o

            const float p = a1 * a2;            // A: i*g     B: f*o
            const float q = cross_half(p);      // A: f*o     B: i*g

            c = __builtin_fmaf(a1, c, q);       // B: f*c + i*g
            h = a2 * ftanh(c);                  // B: o*tanh(c)

            h_hist[tt][lane] = h;               // cols 32..63 hold the real h
        }

        // ---- epilogue: out[b][t0+t'] = x + W_lin . h_t' + b_lin, t' = j
        {
            float facc = 0.0f;
#pragma unroll
            for (int k = 0; k < 32; ++k)
                facc = __builtin_fmaf(W_lin[k], h_hist[j][32 + k], facc);
            if (half == 0)
                ob[t0 + j] = xv + facc + blin;
        }

        xv = xv_next;
    }
}

extern "C" void kernel_launch(void* const* d_in, const int* in_sizes, int n_in,
                              void* d_out, int out_size, void* d_ws, size_t ws_size,
                              hipStream_t stream) {
    const float* x     = (const float*)d_in[0];
    const float* W_ih  = (const float*)d_in[1];
    const float* W_hh  = (const float*)d_in[2];
    const float* b_ih  = (const float*)d_in[3];
    const float* b_hh  = (const float*)d_in[4];
    const float* W_lin = (const float*)d_in[5];
    const float* b_lin = (const float*)d_in[6];
    float* out = (float*)d_out;

    const int B = 64;
    const int T = in_sizes[0] / B;   // 16384

    dim3 grid(B);
    dim3 block(64);
    lstm_wave_scan<<<grid, block, 0, stream>>>(x, W_ih, W_hh, b_ih, b_hh,
                                               W_lin, b_lin, out, T);
}

// Round 7
// 3420.211 us; speedup vs baseline: 1.1400x; 1.0037x over previous
//
#include <hip/hip_runtime.h>

// LSTM scan, B=64, T=16384, H=32, I=O=1, fp32.
// ONE WAVE PER BATCH (64 blocks x 64 threads). ~480 cyc per serial step.
//
// Round-11: SINGLE-VARIABLE experiment. Exact round-4 structure (best
// measured: 3223 us steady) -- same matvec (readlane pairs + packed FMA,
// compiler-scheduled), same epilogue, same LDS layout -- plus ONLY the
// algebraic chain-shortening that rounds 5-8 carried but never isolated
// (it passed with absmax 0.0078125 in all four runs):
//  - exp2 argument scales folded into PRE-SCALED weights/biases; cell state
//    tracked in scaled space C = -2*log2(e)*c. Every transcendental on the
//    serial chain is bare exp2 -> add -> rcp (no leading multiply).
//  - h = o*tanh(c) = fma(sig(2c), 2o, -o); 2o,-o computed off-chain.
//  - A-lane p = KT*i*tanh(g) = fma(r2, 2KT*i, -KT*i); products on the
//    parallel a1 chain.
// Removes ~4 instrs/step, all on the dependence chain (the g2*pa mul, the
// ftanh-internal mul, the post-rcp affine+mul pair): ~20-30 cyc/step.
//
// Post-mortem ledger: R5 (4-chain accs) +instrs -> slower; R6 (PIN) sched
// constraint -> slower; R7 (LDS broadcast) serial DS roundtrip -> slower;
// R8 (scalar fmac + waves_per_eu) weights resident yet slower; R9/10
// (SGPR-pair pk_fma) readlane->SGPR-use hazard -> slightly slower. The R4
// matvec/broadcast form is the local optimum; only the tail algebra is
// untested in isolation.
//
// Lane mapping (validated): j = lane&31, half = lane>>5.
//   A-lanes (half=0): gates i (row j)    and g (row 64+j)
//   B-lanes (half=1): gates f (row 32+j) and o (row 96+j)
// B-lanes hold the real C,h. A-lanes compute bounded garbage: q_A = KT*f*o
// in (KT,0), a1 in (0,1) -> C_A stays negative and finite; h_A in (-1,1).
// Cross-half exchange: permlane32_swap builtin + XOR identity (exact,
// orientation-independent, known-good).

#define HID 32
#define CHUNK 32

typedef float f2 __attribute__((ext_vector_type(2)));
typedef float f4 __attribute__((ext_vector_type(4)));
typedef unsigned int u32x2 __attribute__((ext_vector_type(2)));

#if defined(__has_builtin)
#if __has_builtin(__builtin_amdgcn_permlane32_swap)
#define HAVE_PLSWAP 1
#endif
#endif

__device__ __forceinline__ float rl(float v, int lane) {
    return __int_as_float(__builtin_amdgcn_readlane(__float_as_int(v), lane));
}

// Exchange p across wave halves: every lane gets the other half's p
// (for its own j). VALU-only on gfx950; DS-pipe fallback otherwise.
__device__ __forceinline__ float cross_half(float p) {
#ifdef HAVE_PLSWAP
    const unsigned pu = __float_as_uint(p);
    u32x2 r = __builtin_amdgcn_permlane32_swap(pu, pu, false, false);
    return __uint_as_float(r[0] ^ r[1] ^ pu);   // exact, orientation-independent
#else
    return __shfl_xor(p, 32, 64);
#endif
}

__global__ __launch_bounds__(64, 1)
void lstm_wave_scan(const float* __restrict__ x,
                    const float* __restrict__ W_ih,
                    const float* __restrict__ W_hh,
                    const float* __restrict__ b_ih,
                    const float* __restrict__ b_hh,
                    const float* __restrict__ W_lin,
                    const float* __restrict__ b_lin,
                    float* __restrict__ out,
                    int T) {
    __shared__ float h_hist[CHUNK][65];   // row stride 65: epilogue conflict-free

    const int lane = threadIdx.x;
    const int j    = lane & 31;
    const int half = lane >> 5;
    const int b    = blockIdx.x;

    const int row1 = j + (half << 5);         // A: i-row j     B: f-row 32+j
    const int row2 = 64 + j + (half << 5);    // A: g-row 64+j  B: o-row 96+j

    const float K1 = -1.44269504088896340736f;   // -log2(e): sigmoid arg scale
    const float KT = -2.88539008177792681472f;   // -2*log2(e): tanh-as-sigmoid
    const float K2 = half ? K1 : KT;             // gate2: B=o (sig), A=g (tanh)
    const float cu = half ? KT : 2.0f * KT;      // p = fma(r2, cu*a1, cv*a1)
    const float cv = half ? 0.0f : -KT;          //   (p lives in C-space)

    // Load + pre-scale weights (once; rounding ~1e-7 rel, negligible).
    f2 w1[16], w2[16];
    {
        const f4* R1 = (const f4*)(W_hh + row1 * HID);
        const f4* R2 = (const f4*)(W_hh + row2 * HID);
#pragma unroll
        for (int m = 0; m < 8; ++m) {
            f4 v1 = R1[m];
            w1[2*m]   = f2{v1.x * K1, v1.y * K1};
            w1[2*m+1] = f2{v1.z * K1, v1.w * K1};
            f4 v2 = R2[m];
            w2[2*m]   = f2{v2.x * K2, v2.y * K2};
            w2[2*m+1] = f2{v2.z * K2, v2.w * K2};
        }
    }
    const float wih1 = W_ih[row1] * K1;
    const float bb1  = (b_ih[row1] + b_hh[row1]) * K1;
    const float wih2 = W_ih[row2] * K2;
    const float bb2  = (b_ih[row2] + b_hh[row2]) * K2;
    const float blin = b_lin[0];

    float C = 0.0f;     // B-lanes: KT * cell state  (A-lanes: bounded garbage)
    float h = 0.0f;     // B-lanes: hidden state h_{t-1}

    const float* xb = x   + (size_t)b * T;
    float*       ob = out + (size_t)b * T;

    float xv = xb[j];

    for (int t0 = 0; t0 < T; t0 += CHUNK) {
        int t0n = t0 + CHUNK; if (t0n >= T) t0n = 0;
        float xv_next = xb[t0n + j];

#pragma unroll 8
        for (int tt = 0; tt < CHUNK; ++tt) {
            const float sx = rl(xv, tt);  // wave-uniform x_t

            f2 acc1 = f2{ __builtin_fmaf(sx, wih1, bb1), 0.0f };
            f2 acc2 = f2{ __builtin_fmaf(sx, wih2, bb2), 0.0f };
            // R4 matvec, untouched: readlane pairs feed their packed FMAs
            // directly; compiler schedules broadcast vs. FMA chain.
#pragma unroll
            for (int m = 0; m < 16; ++m) {
                f2 hm = f2{ rl(h, 32 + 2*m), rl(h, 32 + 2*m + 1) };
                acc1 = __builtin_elementwise_fma(w1[m], hm, acc1);
                acc2 = __builtin_elementwise_fma(w2[m], hm, acc2);
            }
            const float m1 = acc1.x + acc1.y;   // A: K1*i-pre   B: K1*f-pre
            const float m2 = acc2.x + acc2.y;   // A: KT*g-pre   B: K1*o-pre

            // bare exp2 -> add -> rcp (scales pre-folded into m1/m2)
            const float a1 = __builtin_amdgcn_rcpf(1.0f + __builtin_amdgcn_exp2f(m1));
            const float r2 = __builtin_amdgcn_rcpf(1.0f + __builtin_amdgcn_exp2f(m2));

            const float uu = cu * a1;       // off the r2 chain (parallel)
            const float vv = cv * a1;
            const float o2 = r2 + r2;       // off the C chain
            const float on = -r2;

            const float p = __builtin_fmaf(r2, uu, vv);
                                            // A: KT*i*tanh(g)   B: KT*f*o
            const float q = cross_half(p);  // A: KT*f*o         B: KT*i*tanh(g)

            C = __builtin_fmaf(a1, C, q);   // B: KT*(f*c + i*g~)
            const float sg = __builtin_amdgcn_rcpf(1.0f + __builtin_amdgcn_exp2f(C));
                                            // B: sigmoid(2c)
            h = __builtin_fmaf(sg, o2, on); // B: o*(2*sig(2c)-1) = o*tanh(c)

            h_hist[tt][lane] = h;           // cols 32..63 hold the real h
        }

        // ---- epilogue: out[b][t0+t'] = x + W_lin . h_t' + b_lin, t' = j
        {
            float facc = 0.0f;
#pragma unroll
            for (int k = 0; k < 32; ++k)
                facc = __builtin_fmaf(W_lin[k], h_hist[j][32 + k], facc);
            if (half == 0)
                ob[t0 + j] = xv + facc + blin;
        }

        xv = xv_next;
    }
}

extern "C" void kernel_launch(void* const* d_in, const int* in_sizes, int n_in,
                              void* d_out, int out_size, void* d_ws, size_t ws_size,
                              hipStream_t stream) {
    const float* x     = (const float*)d_in[0];
    const float* W_ih  = (const float*)d_in[1];
    const float* W_hh  = (const float*)d_in[2];
    const float* b_ih  = (const float*)d_in[3];
    const float* b_hh  = (const float*)d_in[4];
    const float* W_lin = (const float*)d_in[5];
    const float* b_lin = (const float*)d_in[6];
    float* out = (float*)d_out;

    const int B = 64;
    const int T = in_sizes[0] / B;   // 16384

    dim3 grid(B);
    dim3 block(64);
    lstm_wave_scan<<<grid, block, 0, stream>>>(x, W_ih, W_hh, b_ih, b_hh,
                                               W_lin, b_lin, out, T);
}